// Round 19
// baseline (112.011 us; speedup 1.0000x reference)
//
#include <hip/hip_runtime.h>

// MultiAttention fused pipeline for MI355X (gfx950).
// B=1, C=64, H=W=64 (N=4096), NH=8, DK=64, D=512.
// NOTE (r16 lesson): last-block + __threadfence cross-block signalling costs
// ~70us on MI355X (per-XCD L2 writeback) -- never use it here.

#define LOG2E 1.442695040888963f

typedef __attribute__((ext_vector_type(8))) short bf16x8;
typedef __attribute__((ext_vector_type(4))) float f32x4;
typedef __attribute__((ext_vector_type(4))) int i32x4;
typedef __attribute__((ext_vector_type(2))) int i32x2;
typedef __attribute__((ext_vector_type(4))) ushort u16x4;

__device__ __forceinline__ ushort f2bf(float x){
  uint u = __float_as_uint(x);
  u += 0x7fffu + ((u >> 16) & 1u);   // round-to-nearest-even
  return (ushort)(u >> 16);
}
__device__ __forceinline__ float bf2f(ushort h){
  return __uint_as_float(((uint)h) << 16);
}
__device__ __forceinline__ float gelu_(float x){
  return 0.5f * x * (1.0f + erff(x * 0.70710678118654752f));
}
__device__ __forceinline__ float sigmoid_(float x){
  return 1.0f / (1.0f + __expf(-x));
}
__device__ __forceinline__ float exp2_(float x){
  float r; asm("v_exp_f32 %0, %1" : "=v"(r) : "v"(x)); return r;
}
__device__ __forceinline__ int cvtpk(float lo, float hi){
  int r; asm("v_cvt_pk_bf16_f32 %0, %1, %2" : "=v"(r) : "v"(lo), "v"(hi)); return r;
}
__device__ __forceinline__ bf16x8 packf8(const float* s){
  f32x4 x0 = *(const f32x4*)s;
  f32x4 x1 = *(const f32x4*)(s+4);
  union{ i32x4 i; bf16x8 v; } u;
  u.i[0]=cvtpk(x0[0],x0[1]); u.i[1]=cvtpk(x0[2],x0[3]);
  u.i[2]=cvtpk(x1[0],x1[1]); u.i[3]=cvtpk(x1[2],x1[3]);
  return u.v;
}
// async global->LDS, 16B per lane; LDS dest = wave-uniform base + lane*16
__device__ __forceinline__ void gload16(const ushort* g, ushort* l){
  __builtin_amdgcn_global_load_lds(
    (const __attribute__((address_space(1))) uint*)(const void*)g,
    (__attribute__((address_space(3))) uint*)(void*)l, 16, 0, 0);
}

// ---------------- D1: fused QKV projection (y=0) ; pe-branch + wprep (y=1) -
__global__ __launch_bounds__(256) void k_qkv(const float* __restrict__ xin,
    const float* __restrict__ Wq, const float* __restrict__ Wk,
    const float* __restrict__ Wv, const float* __restrict__ scale,
    ushort* __restrict__ q_bf, ushort* __restrict__ k_bf, ushort* __restrict__ vT,
    const float* __restrict__ pe_w1, const float* __restrict__ pe_w2,
    float* __restrict__ embed, const float* __restrict__ Wout,
    const float* __restrict__ si_w1, ushort* __restrict__ Woutb,
    ushort* __restrict__ si_w1b, float* __restrict__ pooled){
  __shared__ float t0[20*64];
  __shared__ float t1[18*64];
  const int tid = threadIdx.x;
  if (blockIdx.y == 1){
    if (tid < 192){
      int i = blockIdx.x*192 + tid;
      if (i < 32768) Woutb[i] = f2bf(Wout[i]);
      else           si_w1b[i - 32768] = f2bf(si_w1[i - 32768]);
    }
    if (blockIdx.x == 0){ pooled[tid] = 0.f; pooled[tid+256] = 0.f; }
    const int c = blockIdx.x >> 2;
    const int r0 = (blockIdx.x & 3) * 16;
    const float* src = xin + (size_t)c*4096;
#pragma unroll
    for (int i=0;i<5;i++){
      int idx = tid + 256*i;
      if (idx < 1280){
        int lr = idx >> 6, x = idx & 63;
        int gr = r0 - 2 + lr;
        t0[idx] = (gr >= 0 && gr < 64) ? src[gr*64 + x] : 0.f;
      }
    }
    __syncthreads();
    float w1[9], w2[9];
#pragma unroll
    for (int i=0;i<9;i++){ w1[i] = pe_w1[c*9+i]; w2[i] = pe_w2[c*9+i]; }
#pragma unroll
    for (int i=0;i<5;i++){
      int idx = tid + 256*i;
      if (idx < 1152){
        int lr = idx >> 6, x = idx & 63;
        int gr = r0 - 1 + lr;
        float acc = 0.f;
        if (gr >= 0 && gr < 64){
#pragma unroll
          for (int ky=0;ky<3;ky++){
            int gy = gr + ky - 1;
            if (gy < 0 || gy > 63) continue;
#pragma unroll
            for (int kx=0;kx<3;kx++){
              int xx = x + kx - 1;
              if (xx < 0 || xx > 63) continue;
              acc += w1[ky*3+kx] * t0[(lr + ky)*64 + xx];
            }
          }
          acc = gelu_(acc);
        }
        t1[idx] = acc;
      }
    }
    __syncthreads();
    float* dst = embed + (size_t)c*4096;
#pragma unroll
    for (int i=0;i<4;i++){
      int idx = tid + 256*i;
      int lr = idx >> 6, x = idx & 63;
      int gr = r0 + lr;
      float acc = 0.f;
#pragma unroll
      for (int ky=0;ky<3;ky++){
        int gy = gr + ky - 1;
        if (gy < 0 || gy > 63) continue;
#pragma unroll
        for (int kx=0;kx<3;kx++){
          int xx = x + kx - 1;
          if (xx < 0 || xx > 63) continue;
          acc += w2[ky*3+kx] * t1[(lr + ky)*64 + xx];
        }
      }
      dst[gr*64 + x] = acc;
    }
    return;
  }
  // ---- fused QKV: one block does q, k, v for its 16-row strip (A reused) --
  const int n0 = blockIdx.x * 16;
  const int lane = tid & 63, w = tid >> 6;
  const int l15 = lane & 15, g = lane >> 4;
  const int obase = w * 128;
  const int n = n0 + l15;
  float xa[8], xc[8];
#pragma unroll
  for (int j=0;j<8;j++){
    xa[j] = xin[(8*g + j)*4096 + n];
    xc[j] = xin[(32 + 8*g + j)*4096 + n];
  }
  union{ i32x4 i; bf16x8 v; } ua, uc;
  ua.i[0]=cvtpk(xa[0],xa[1]); ua.i[1]=cvtpk(xa[2],xa[3]);
  ua.i[2]=cvtpk(xa[4],xa[5]); ua.i[3]=cvtpk(xa[6],xa[7]);
  uc.i[0]=cvtpk(xc[0],xc[1]); uc.i[1]=cvtpk(xc[2],xc[3]);
  uc.i[2]=cvtpk(xc[4],xc[5]); uc.i[3]=cvtpk(xc[6],xc[7]);
  const bf16x8 a0 = ua.v, a1 = uc.v;
  const float* Ws[3] = { Wq, Wk, Wv };
  for (int z=0; z<3; ++z){
    const float* W = Ws[z];
    f32x4 acc[8];
#pragma unroll
    for (int t=0;t<8;t++) acc[t] = (f32x4){0.f,0.f,0.f,0.f};
#pragma unroll
    for (int t=0;t<8;t++){
      const float* brow = W + (size_t)(obase + 16*t + l15)*64;
      bf16x8 b0 = packf8(brow + 8*g);
      bf16x8 b1 = packf8(brow + 32 + 8*g);
      acc[t] = __builtin_amdgcn_mfma_f32_16x16x32_bf16(a0, b0, acc[t], 0,0,0);
      acc[t] = __builtin_amdgcn_mfma_f32_16x16x32_bf16(a1, b1, acc[t], 0,0,0);
    }
    if (z < 2){
#pragma unroll
      for (int hh=0; hh<2; hh++){
        float sfac = (z==0) ? (scale[2*w+hh] * LOG2E) : 1.0f;
#pragma unroll
        for (int r=0;r<4;r++){
          float ss = 0.f;
#pragma unroll
          for (int tt=0;tt<4;tt++){ float v = acc[hh*4+tt][r]; ss += v*v; }
          ss += __shfl_xor(ss, 1); ss += __shfl_xor(ss, 2);
          ss += __shfl_xor(ss, 4); ss += __shfl_xor(ss, 8);
          float inv = sfac / fmaxf(sqrtf(ss), 1e-12f);
#pragma unroll
          for (int tt=0;tt<4;tt++) acc[hh*4+tt][r] *= inv;
        }
      }
      ushort* dst = (z==0) ? q_bf : k_bf;
#pragma unroll
      for (int t=0;t<8;t++){
        int col = obase + 16*t + l15;
#pragma unroll
        for (int r=0;r<4;r++)
          dst[(size_t)(n0 + 4*g + r)*512 + col] = f2bf(acc[t][r]);
      }
    } else {
#pragma unroll
      for (int t=0;t<8;t++){
        int col = obase + 16*t + l15;
        u16x4 vs;
#pragma unroll
        for (int r=0;r<4;r++) vs[r] = f2bf(acc[t][r]);
        *(u16x4*)(vT + (size_t)col*4096 + n0 + 4*g) = vs;
      }
    }
  }
}

// ---------------- D2: flash attention (8 waves x 32 q-rows, KVB=128) + conv
// attn blocks [0, NA): 512 thr = 8 waves, KVB=128 (8 barriers/block @S=4),
// K+V LDS dbuf (64 KB), staged via global_load_lds (2K+2V instr per wave).
// conv blocks [NA, NA+512): depthwise 3x3 + BN + GELU (8 px/thread).
__global__ __launch_bounds__(512) void k_attn_conv(const ushort* __restrict__ q_bf,
    const ushort* __restrict__ k_bf, const ushort* __restrict__ vT,
    ushort* __restrict__ O_part, float* __restrict__ lsum_part, int log2S,
    const float* __restrict__ dw_w, const float* __restrict__ dw_b,
    const float* __restrict__ dw_g, const float* __restrict__ dw_bt,
    const float* __restrict__ dw_m, const float* __restrict__ dw_v,
    ushort* __restrict__ conv_x){
  __shared__ ushort Kt[2][8192];   // [128 key][64 d], swizzled
  __shared__ ushort Vt[2][8192];   // [64 d][128 key], swizzled
  const int S = 1 << log2S;
  const int NA = 128 << log2S;
  const int bid = blockIdx.x;
  const int tid = threadIdx.x;

  if (bid >= NA){
    float* tile = (float*)&Kt[0][0];
    const int d = bid - NA;
    const ushort* src = vT + (size_t)d*4096;
#pragma unroll
    for (int j=0;j<2;j++){
      u16x4 va = *(const u16x4*)(src + tid*4 + 2048*j);
      f32x4 vf;
#pragma unroll
      for (int i=0;i<4;i++) vf[i] = bf2f(va[i]);
      *(f32x4*)&tile[tid*4 + 2048*j] = vf;
    }
    __syncthreads();
    float wv[9];
#pragma unroll
    for (int i=0;i<9;i++) wv[i] = dw_w[d*9+i];
    const float bias = dw_b[d];
    const float bnsc = dw_g[d] * rsqrtf(dw_v[d] + 1e-5f);
    const float bnb  = dw_bt[d] - dw_m[d]*bnsc;
    ushort* dst = conv_x + (size_t)d*4096;
#pragma unroll 4
    for (int i=0;i<8;i++){
      int p = tid + 512*i;
      int y = p >> 6, x = p & 63;
      float acc = 0.f;
#pragma unroll
      for (int ky=0;ky<3;ky++){
        int yy = y + ky - 1;
        if (yy < 0 || yy > 63) continue;
#pragma unroll
        for (int kx=0;kx<3;kx++){
          int xx = x + kx - 1;
          if (xx < 0 || xx > 63) continue;
          acc += wv[ky*3+kx] * tile[yy*64 + xx];
        }
      }
      float cc = (acc + bias)*bnsc + bnb;
      dst[p] = f2bf(gelu_(cc));
    }
    return;
  }
  const int combo = bid & (8*S - 1);
  const int qb = bid >> (3 + log2S);
  const int h = combo >> log2S;
  const int seg = combo & (S - 1);
  const int kv0 = seg * (4096 >> log2S);
  const int iters = (4096 >> log2S) >> 7;   // KVB=128
  const int lane = tid & 63, w = tid >> 6;   // 8 waves
  const int l15 = lane & 15, g = lane >> 4;

  // K staging: wave w covers key-rows w*16..w*16+15 via 2 gload16.
  // lane l -> row +(l>>3), stored chunk l&7, content chunk (l&7)^(l>>3).
  const int lr8 = lane >> 3;
  const int swzcK = ((lane & 7) ^ lr8) << 3;
  const ushort* kSrc0 = k_bf + (size_t)(kv0 + w*16 + lr8)*512 + h*64 + swzcK;
  const ushort* kSrc1 = kSrc0 + (size_t)8*512;
  // V staging: wave w covers d-rows w*8..w*8+7 via 2 gload16 (4 rows each).
  // lane l -> row +(l>>4), stored chunk l&15, content chunk (l&15)^(row&7).
  const int vr0 = w*8 + (lane >> 4);          // rows for instr 0
  const int vr1 = vr0 + 4;                    // rows for instr 1
  const ushort* vSrc0 = vT + (size_t)(h*64 + vr0)*4096 + kv0
                        + (((lane & 15) ^ (vr0 & 7)) << 3);
  const ushort* vSrc1 = vT + (size_t)(h*64 + vr1)*4096 + kv0
                        + (((lane & 15) ^ (vr1 & 7)) << 3);
  ushort* kl0[2] = { &Kt[0][(w*16)*64],   &Kt[1][(w*16)*64] };
  ushort* kl1[2] = { &Kt[0][(w*16+8)*64], &Kt[1][(w*16+8)*64] };
  ushort* vl0[2] = { &Vt[0][(w*8)*128],   &Vt[1][(w*8)*128] };
  ushort* vl1[2] = { &Vt[0][(w*8+4)*128], &Vt[1][(w*8+4)*128] };

  const int qrow0 = qb*256 + w*32;
  bf16x8 qa[2][2];
#pragma unroll
  for (int tq=0;tq<2;tq++){
    const ushort* qrow = q_bf + (size_t)(qrow0 + tq*16 + l15)*512 + h*64;
    qa[tq][0] = *(const bf16x8*)(qrow + 8*g);
    qa[tq][1] = *(const bf16x8*)(qrow + 32 + 8*g);
  }
  f32x4 O[2][4];
#pragma unroll
  for (int tq=0;tq<2;tq++)
#pragma unroll
    for (int t=0;t<4;t++) O[tq][t] = (f32x4){0.f,0.f,0.f,0.f};
  float lsum[2] = {0.f,0.f};

  gload16(kSrc0, kl0[0]); gload16(kSrc1, kl1[0]);
  gload16(vSrc0, vl0[0]); gload16(vSrc1, vl1[0]);
  asm volatile("s_waitcnt vmcnt(0)" ::: "memory");
  __builtin_amdgcn_s_barrier();

  const int x7 = l15 & 7;
  const int gq = g >> 1, gh2 = (g & 1) << 2;

  for (int it = 0; it < iters; ++it){
    const int buf = it & 1;
    if (it + 1 < iters){
      kSrc0 += 128*512; kSrc1 += 128*512; vSrc0 += 128; vSrc1 += 128;
      gload16(kSrc0, kl0[buf^1]); gload16(kSrc1, kl1[buf^1]);
      gload16(vSrc0, vl0[buf^1]); gload16(vSrc1, vl1[buf^1]);
    }
    const ushort* Kb = Kt[buf];
    const ushort* Vb = Vt[buf];
#pragma unroll
    for (int ks=0; ks<4; ++ks){
      i32x4 PA[2];
#pragma unroll
      for (int s2=0; s2<2; ++s2){
        const int rr = 16*(2*ks + s2) + l15;
        bf16x8 kf0 = *(const bf16x8*)&Kb[rr*64 + ((g     ^ x7) << 3)];
        bf16x8 kf1 = *(const bf16x8*)&Kb[rr*64 + (((4+g) ^ x7) << 3)];
        const int hi = s2 << 1;
#pragma unroll
        for (int tq=0; tq<2; ++tq){
          f32x4 st = (f32x4){0.f,0.f,0.f,0.f};
          st = __builtin_amdgcn_mfma_f32_16x16x32_bf16(kf0, qa[tq][0], st, 0,0,0);
          st = __builtin_amdgcn_mfma_f32_16x16x32_bf16(kf1, qa[tq][1], st, 0,0,0);
          float p0 = exp2_(st[0]), p1 = exp2_(st[1]);
          float p2 = exp2_(st[2]), p3 = exp2_(st[3]);
          lsum[tq] += (p0 + p1) + (p2 + p3);
          PA[tq][hi]   = cvtpk(p0, p1);
          PA[tq][hi+1] = cvtpk(p2, p3);
        }
      }
      __builtin_amdgcn_s_setprio(1);
#pragma unroll
      for (int t=0;t<4;++t){
        const int rr = 16*t + l15;
        const int c0 = 4*ks + gq, c1 = 4*ks + 2 + gq;
        union { bf16x8 v; i32x2 h2[2]; } u;
        u.h2[0] = *(const i32x2*)&Vb[rr*128 + ((c0 ^ x7) << 3) + gh2];
        u.h2[1] = *(const i32x2*)&Vb[rr*128 + ((c1 ^ x7) << 3) + gh2];
#pragma unroll
        for (int tq=0;tq<2;++tq){
          union { i32x4 i; bf16x8 v; } a; a.i = PA[tq];
          O[tq][t] = __builtin_amdgcn_mfma_f32_16x16x32_bf16(a.v, u.v, O[tq][t], 0,0,0);
        }
      }
      __builtin_amdgcn_s_setprio(0);
    }
    asm volatile("s_waitcnt vmcnt(0)" ::: "memory");
    __builtin_amdgcn_s_barrier();
  }
#pragma unroll
  for (int tq=0;tq<2;tq++){
    float ls = lsum[tq];
    ls += __shfl_xor(ls, 16); ls += __shfl_xor(ls, 32);
    if (g == 0)
      lsum_part[((size_t)seg*8 + h)*4096 + qrow0 + tq*16 + l15] = ls;
  }
  ushort* Op = O_part + (size_t)seg*4096*512;
#pragma unroll
  for (int tq=0;tq<2;tq++)
#pragma unroll
    for (int t=0;t<4;t++)
#pragma unroll
      for (int r=0;r<4;r++)
        Op[(size_t)(qrow0 + tq*16 + 4*g + r)*512 + h*64 + 16*t + l15] = f2bf(O[tq][t][r]);
}

// ---------------- D3: combine kv-split partials (templated, vectorized) ----
// 256 blocks x 256 thr, 16 n-rows/block. Thread = (d-chunk of 8, 4 n-rows).
template<int S>
__global__ __launch_bounds__(256) void k_comb_t(const ushort* __restrict__ O_part,
    const float* __restrict__ lsum_part, ushort* __restrict__ att_bf,
    float* __restrict__ pooled){
  __shared__ float Linv[16][8];
  __shared__ float red[4][512];
  const int qbase = blockIdx.x * 16;
  const int tid = threadIdx.x;
  if (tid < 128){
    int q = tid >> 3, h = tid & 7;
    float L = 0.f;
#pragma unroll
    for (int s=0;s<S;s++) L += lsum_part[((size_t)s*8 + h)*4096 + qbase + q];
    Linv[q][h] = 1.0f / L;
  }
  __syncthreads();
  const int ch = tid & 63;        // d-chunk (8 elems)
  const int qg = tid >> 6;        // 0..3
  const int d0 = ch * 8;
  const int hh = ch >> 3;
  float pool[8] = {0.f,0.f,0.f,0.f,0.f,0.f,0.f,0.f};
#pragma unroll
  for (int qq=0; qq<4; qq++){
    const int q = qg*4 + qq;
    const size_t idx = (size_t)(qbase + q)*512 + d0;
    i32x4 seg[S];
#pragma unroll
    for (int s=0;s<S;s++)
      seg[s] = *(const i32x4*)(O_part + (size_t)s*4096*512 + idx);
    float o[8];
#pragma unroll
    for (int j=0;j<8;j++){
      uint pk = ((const uint*)&seg[0])[j>>1];
      o[j] = bf2f((ushort)(pk >> ((j&1)*16)));
    }
#pragma unroll
    for (int s=1;s<S;s++)
#pragma unroll
      for (int j=0;j<8;j++){
        uint pk = ((const uint*)&seg[s])[j>>1];
        o[j] += bf2f((ushort)(pk >> ((j&1)*16)));
      }
    const float li = Linv[q][hh];
    union{ i32x4 i; } w;
#pragma unroll
    for (int j=0;j<8;j++){ o[j] *= li; pool[j] += o[j]; }
    w.i[0]=cvtpk(o[0],o[1]); w.i[1]=cvtpk(o[2],o[3]);
    w.i[2]=cvtpk(o[4],o[5]); w.i[3]=cvtpk(o[6],o[7]);
    *(i32x4*)(att_bf + idx) = w.i;
  }
  *(f32x4*)&red[qg][d0]     = *(f32x4*)&pool[0];
  *(f32x4*)&red[qg][d0 + 4] = *(f32x4*)&pool[4];
  __syncthreads();
  {
    int d = tid;
    float s0 = red[0][d] + red[1][d] + red[2][d] + red[3][d];
    int d2 = tid + 256;
    float s1 = red[0][d2] + red[1][d2] + red[2][d2] + red[3][d2];
    atomicAdd(&pooled[d], s0);
    atomicAdd(&pooled[d2], s1);
  }
}

// ---------------- D4: MLP + conv-transpose + spatial-SE + gate GEMM + embed
// 512 threads (8 waves), K-split 8x64. conv slice transposed in-LDS.
__global__ __launch_bounds__(512) void k_final(const ushort* __restrict__ att_bf,
    const ushort* __restrict__ conv_x, const ushort* __restrict__ si_w1b,
    const float* __restrict__ si_b1, const float* __restrict__ si_g,
    const float* __restrict__ si_bt, const float* __restrict__ si_m,
    const float* __restrict__ si_v, const float* __restrict__ si_w2,
    const float* __restrict__ si_b2,
    const float* __restrict__ pooled, const float* __restrict__ ci_w1,
    const float* __restrict__ ci_b1, const float* __restrict__ ci_w2,
    const float* __restrict__ ci_b2,
    const ushort* __restrict__ Woutb, const float* __restrict__ bout,
    const float* __restrict__ embed, float* __restrict__ out){
  __shared__ ushort ct[16*520];           // [n-local][d], padded rows
  __shared__ float pl[512];
  __shared__ float h1[128];
  __shared__ float scm[512];
  __shared__ f32x4 part2[8][2][64];
  __shared__ float smv[16];
  __shared__ f32x4 part[8][4][64];
  const int tid = threadIdx.x;
  const int lane = tid & 63, w = tid >> 6;       // 8 waves
  const int l15 = lane & 15, g = lane >> 4;
  const int n0 = blockIdx.x * 16;
  const int rowA = n0 + l15;
  // stage: pooled/4096 + conv slice transpose (thread t = d-row t)
  pl[tid] = pooled[tid] * (1.0f/4096.0f);
  {
    const ushort* s = conv_x + (size_t)tid*4096 + n0;
    union{ i32x4 q[2]; ushort e[16]; } u;
    u.q[0] = *(const i32x4*)s;
    u.q[1] = *(const i32x4*)(s + 8);
#pragma unroll
    for (int j=0;j<16;j++) ct[j*520 + tid] = u.e[j];
  }
  // att fragments (K chunk = w*64)
  bf16x8 at8[2];
#pragma unroll
  for (int kk=0;kk<2;kk++){
    int k0 = w*64 + kk*32 + 8*g;
    at8[kk] = *(const bf16x8*)(att_bf + (size_t)rowA*512 + k0);
  }
  __syncthreads();
  // channel MLP layer 1: all 512 threads, e = tid>>2, quarter-K + 2 shfl
  {
    int e = tid >> 2;
    int base = (tid & 3) * 128;
    float acc = 0.f;
    const float* wr = ci_w1 + (size_t)e*512 + base;
#pragma unroll 8
    for (int c=0;c<128;c++) acc += wr[c]*pl[base + c];
    acc += __shfl_xor(acc, 1);
    acc += __shfl_xor(acc, 2);
    if (!(tid & 3)) h1[e] = gelu_(acc + ci_b1[e]);
  }
  // conv fragments from transposed LDS
  bf16x8 cn8[2];
#pragma unroll
  for (int kk=0;kk<2;kk++){
    int k0 = w*64 + kk*32 + 8*g;
    cn8[kk] = *(const bf16x8*)&ct[l15*520 + k0];
  }
  __syncthreads();
  // channel MLP layer 2: d = tid (512)
  {
    float acc = ci_b2[tid];
    const float* wr = ci_w2 + (size_t)tid*128;
#pragma unroll 8
    for (int e=0;e<128;e++) acc += wr[e]*h1[e];
    scm[tid] = sigmoid_(acc);
  }
  // spatial: s1 = conv . si_w1^T (32 e), K-split by wave
  f32x4 a2[2];
  a2[0] = (f32x4){0.f,0.f,0.f,0.f};
  a2[1] = (f32x4){0.f,0.f,0.f,0.f};
#pragma unroll
  for (int kk=0;kk<2;kk++){
    int k0 = w*64 + kk*32 + 8*g;
#pragma unroll
    for (int t=0;t<2;t++){
      bf16x8 b = *(const bf16x8*)(si_w1b + (size_t)(16*t + l15)*512 + k0);
      a2[t] = __builtin_amdgcn_mfma_f32_16x16x32_bf16(cn8[kk], b, a2[t], 0,0,0);
    }
  }
  part2[w][0][lane] = a2[0];
  part2[w][1][lane] = a2[1];
  __syncthreads();
  if (w == 0){
    float rowv[4] = {0.f,0.f,0.f,0.f};
#pragma unroll
    for (int t=0;t<2;t++){
      f32x4 s4 = part2[0][t][lane];
#pragma unroll
      for (int ww=1;ww<8;ww++) s4 = s4 + part2[ww][t][lane];
      int e = 16*t + l15;
      float s = si_g[e] * rsqrtf(si_v[e] + 1e-5f);
      float b1 = si_b1[e] - si_m[e];
      float bt = si_bt[e];
      float w2e = si_w2[e];
#pragma unroll
      for (int r=0;r<4;r++){
        float v = (s4[r] + b1)*s + bt;
        rowv[r] += w2e * gelu_(v);
      }
    }
    float sb2 = si_b2[0];
#pragma unroll
    for (int r=0;r<4;r++){
      float v = rowv[r];
      v += __shfl_xor(v,1); v += __shfl_xor(v,2);
      v += __shfl_xor(v,4); v += __shfl_xor(v,8);
      if (l15 == 0) smv[4*g + r] = sigmoid_(v + sb2);
    }
  }
  __syncthreads();
  const float srow = smv[l15];
  // gate + output GEMM (K chunk = w*64)
  f32x4 acc[4];
#pragma unroll
  for (int t=0;t<4;t++) acc[t] = (f32x4){0.f,0.f,0.f,0.f};
#pragma unroll
  for (int kk=0;kk<2;kk++){
    int k0 = w*64 + kk*32 + 8*g;
    bf16x8 af;
#pragma unroll
    for (int i=0;i<8;i++){
      int d = k0 + i;
      float zv = bf2f((ushort)at8[kk][i]) * srow + bf2f((ushort)cn8[kk][i]) * scm[d];
      af[i] = (short)f2bf(zv);
    }
#pragma unroll
    for (int t=0;t<4;t++){
      bf16x8 bf8 = *(const bf16x8*)(Woutb + (size_t)(16*t+l15)*512 + k0);
      acc[t] = __builtin_amdgcn_mfma_f32_16x16x32_bf16(af, bf8, acc[t], 0,0,0);
    }
  }
#pragma unroll
  for (int t=0;t<4;t++) part[w][t][lane] = acc[t];
  __syncthreads();
  if (w < 4){
    f32x4 s4 = part[0][w][lane];
#pragma unroll
    for (int ww=1;ww<8;ww++) s4 = s4 + part[ww][w][lane];
    int o = 16*w + l15;
    float bo = bout[o];
#pragma unroll
    for (int r=0;r<4;r++){
      int row = n0 + 4*g + r;
      size_t idx = (size_t)row*64 + o;
      out[idx] = s4[r] + bo + embed[idx];
    }
  }
}

extern "C" void kernel_launch(void* const* d_in, const int* in_sizes, int n_in,
                              void* d_out, int out_size, void* d_ws, size_t ws_size,
                              hipStream_t stream){
  (void)in_sizes; (void)n_in; (void)out_size;
  const float* x_in  = (const float*)d_in[0];
  const float* Wq    = (const float*)d_in[1];
  const float* Wk    = (const float*)d_in[2];
  const float* Wv    = (const float*)d_in[3];
  const float* scale = (const float*)d_in[4];
  const float* Wout  = (const float*)d_in[5];
  const float* bout  = (const float*)d_in[6];
  const float* dw_w  = (const float*)d_in[7];
  const float* dw_b  = (const float*)d_in[8];
  const float* dw_g  = (const float*)d_in[9];
  const float* dw_bt = (const float*)d_in[10];
  const float* dw_m  = (const float*)d_in[11];
  const float* dw_v  = (const float*)d_in[12];
  const float* ci_w1 = (const float*)d_in[13];
  const float* ci_b1 = (const float*)d_in[14];
  const float* ci_w2 = (const float*)d_in[15];
  const float* ci_b2 = (const float*)d_in[16];
  const float* si_w1 = (const float*)d_in[17];
  const float* si_b1 = (const float*)d_in[18];
  const float* si_g  = (const float*)d_in[19];
  const float* si_bt = (const float*)d_in[20];
  const float* si_m  = (const float*)d_in[21];
  const float* si_v  = (const float*)d_in[22];
  const float* si_w2 = (const float*)d_in[23];
  const float* si_b2 = (const float*)d_in[24];
  const float* pe_w1 = (const float*)d_in[25];
  const float* pe_w2 = (const float*)d_in[26];
  float* out = (float*)d_out;

  char* p = (char*)d_ws;
  auto alloc = [&](size_t bytes)->char*{
    char* r = p; p += (bytes + 255) & ~(size_t)255; return r;
  };
  ushort* q_bf    = (ushort*)alloc((size_t)4096*512*2);
  ushort* k_bf    = (ushort*)alloc((size_t)4096*512*2);
  ushort* vTb     = (ushort*)alloc((size_t)512*4096*2);
  ushort* att_bf  = (ushort*)alloc((size_t)4096*512*2);
  ushort* conv_x  = (ushort*)alloc((size_t)512*4096*2);
  ushort* Woutb   = (ushort*)alloc((size_t)32768*2);
  ushort* si_w1b  = (ushort*)alloc((size_t)16384*2);
  float*  embed   = (float*) alloc((size_t)64*4096*4);
  float*  lsum_p  = (float*) alloc((size_t)8*8*4096*4);
  float*  pooled  = (float*) alloc(512*4);
  size_t used = (size_t)(p - (char*)d_ws);
  size_t segBytes = (size_t)4096*512*2 + 256;   // bf16 partials
  size_t avail = (ws_size > used) ? (ws_size - used) : 0;
  int log2S = 2;
  if (avail < 4*segBytes) log2S = 1;
  if (avail < 2*segBytes) log2S = 0;
  int S = 1 << log2S;
  ushort* O_part = (ushort*)alloc((size_t)S*segBytes);
  int NA = 128 << log2S;

  k_qkv<<<dim3(256,2), 256, 0, stream>>>(x_in, Wq, Wk, Wv, scale, q_bf, k_bf, vTb,
                                         pe_w1, pe_w2, embed, Wout, si_w1,
                                         Woutb, si_w1b, pooled);
  k_attn_conv<<<NA + 512, 512, 0, stream>>>(q_bf, k_bf, vTb, O_part, lsum_p, log2S,
                                            dw_w, dw_b, dw_g, dw_bt, dw_m, dw_v,
                                            conv_x);
  if (log2S == 2)
    k_comb_t<4><<<256, 256, 0, stream>>>(O_part, lsum_p, att_bf, pooled);
  else if (log2S == 1)
    k_comb_t<2><<<256, 256, 0, stream>>>(O_part, lsum_p, att_bf, pooled);
  else
    k_comb_t<1><<<256, 256, 0, stream>>>(O_part, lsum_p, att_bf, pooled);
  k_final<<<256, 512, 0, stream>>>(att_bf, conv_x, si_w1b, si_b1, si_g, si_bt,
                                   si_m, si_v, si_w2, si_b2,
                                   pooled, ci_w1, ci_b1, ci_w2, ci_b2,
                                   Woutb, bout, embed, out);
}

// Round 20
// 100.779 us; speedup vs baseline: 1.1115x; 1.1115x over previous
//
#include <hip/hip_runtime.h>

// MultiAttention fused pipeline for MI355X (gfx950).
// B=1, C=64, H=W=64 (N=4096), NH=8, DK=64, D=512.
// NOTE (r16 lesson): last-block + __threadfence cross-block signalling costs
// ~70us on MI355X (per-XCD L2 writeback) -- never use it here.
// NOTE (r19 lesson): KVB=128 (64KB LDS dbuf) drops occupancy 34->19% and
// regresses attn 48->60us; KVB=64 is optimal for the 8-wave structure.

#define LOG2E 1.442695040888963f

typedef __attribute__((ext_vector_type(8))) short bf16x8;
typedef __attribute__((ext_vector_type(4))) float f32x4;
typedef __attribute__((ext_vector_type(4))) int i32x4;
typedef __attribute__((ext_vector_type(2))) int i32x2;
typedef __attribute__((ext_vector_type(4))) ushort u16x4;

__device__ __forceinline__ ushort f2bf(float x){
  uint u = __float_as_uint(x);
  u += 0x7fffu + ((u >> 16) & 1u);   // round-to-nearest-even
  return (ushort)(u >> 16);
}
__device__ __forceinline__ float bf2f(ushort h){
  return __uint_as_float(((uint)h) << 16);
}
__device__ __forceinline__ float gelu_(float x){
  return 0.5f * x * (1.0f + erff(x * 0.70710678118654752f));
}
__device__ __forceinline__ float sigmoid_(float x){
  return 1.0f / (1.0f + __expf(-x));
}
__device__ __forceinline__ float exp2_(float x){
  float r; asm("v_exp_f32 %0, %1" : "=v"(r) : "v"(x)); return r;
}
__device__ __forceinline__ int cvtpk(float lo, float hi){
  int r; asm("v_cvt_pk_bf16_f32 %0, %1, %2" : "=v"(r) : "v"(lo), "v"(hi)); return r;
}
__device__ __forceinline__ bf16x8 packf8(const float* s){
  f32x4 x0 = *(const f32x4*)s;
  f32x4 x1 = *(const f32x4*)(s+4);
  union{ i32x4 i; bf16x8 v; } u;
  u.i[0]=cvtpk(x0[0],x0[1]); u.i[1]=cvtpk(x0[2],x0[3]);
  u.i[2]=cvtpk(x1[0],x1[1]); u.i[3]=cvtpk(x1[2],x1[3]);
  return u.v;
}
// async global->LDS, 16B per lane; LDS dest = wave-uniform base + lane*16
__device__ __forceinline__ void gload16(const ushort* g, ushort* l){
  __builtin_amdgcn_global_load_lds(
    (const __attribute__((address_space(1))) uint*)(const void*)g,
    (__attribute__((address_space(3))) uint*)(void*)l, 16, 0, 0);
}

// ---------------- D1: fused QKV projection (y=0) ; pe-branch + wprep (y=1) -
__global__ __launch_bounds__(256) void k_qkv(const float* __restrict__ xin,
    const float* __restrict__ Wq, const float* __restrict__ Wk,
    const float* __restrict__ Wv, const float* __restrict__ scale,
    ushort* __restrict__ q_bf, ushort* __restrict__ k_bf, ushort* __restrict__ vT,
    const float* __restrict__ pe_w1, const float* __restrict__ pe_w2,
    float* __restrict__ embed, const float* __restrict__ Wout,
    const float* __restrict__ si_w1, ushort* __restrict__ Woutb,
    ushort* __restrict__ si_w1b, float* __restrict__ pooled){
  __shared__ float t0[20*64];
  __shared__ float t1[18*64];
  const int tid = threadIdx.x;
  if (blockIdx.y == 1){
    if (tid < 192){
      int i = blockIdx.x*192 + tid;
      if (i < 32768) Woutb[i] = f2bf(Wout[i]);
      else           si_w1b[i - 32768] = f2bf(si_w1[i - 32768]);
    }
    if (blockIdx.x == 0){ pooled[tid] = 0.f; pooled[tid+256] = 0.f; }
    const int c = blockIdx.x >> 2;
    const int r0 = (blockIdx.x & 3) * 16;
    const float* src = xin + (size_t)c*4096;
#pragma unroll
    for (int i=0;i<5;i++){
      int idx = tid + 256*i;
      if (idx < 1280){
        int lr = idx >> 6, x = idx & 63;
        int gr = r0 - 2 + lr;
        t0[idx] = (gr >= 0 && gr < 64) ? src[gr*64 + x] : 0.f;
      }
    }
    __syncthreads();
    float w1[9], w2[9];
#pragma unroll
    for (int i=0;i<9;i++){ w1[i] = pe_w1[c*9+i]; w2[i] = pe_w2[c*9+i]; }
#pragma unroll
    for (int i=0;i<5;i++){
      int idx = tid + 256*i;
      if (idx < 1152){
        int lr = idx >> 6, x = idx & 63;
        int gr = r0 - 1 + lr;
        float acc = 0.f;
        if (gr >= 0 && gr < 64){
#pragma unroll
          for (int ky=0;ky<3;ky++){
            int gy = gr + ky - 1;
            if (gy < 0 || gy > 63) continue;
#pragma unroll
            for (int kx=0;kx<3;kx++){
              int xx = x + kx - 1;
              if (xx < 0 || xx > 63) continue;
              acc += w1[ky*3+kx] * t0[(lr + ky)*64 + xx];
            }
          }
          acc = gelu_(acc);
        }
        t1[idx] = acc;
      }
    }
    __syncthreads();
    float* dst = embed + (size_t)c*4096;
#pragma unroll
    for (int i=0;i<4;i++){
      int idx = tid + 256*i;
      int lr = idx >> 6, x = idx & 63;
      int gr = r0 + lr;
      float acc = 0.f;
#pragma unroll
      for (int ky=0;ky<3;ky++){
        int gy = gr + ky - 1;
        if (gy < 0 || gy > 63) continue;
#pragma unroll
        for (int kx=0;kx<3;kx++){
          int xx = x + kx - 1;
          if (xx < 0 || xx > 63) continue;
          acc += w2[ky*3+kx] * t1[(lr + ky)*64 + xx];
        }
      }
      dst[gr*64 + x] = acc;
    }
    return;
  }
  // ---- fused QKV: one block does q, k, v for its 16-row strip (A reused) --
  const int n0 = blockIdx.x * 16;
  const int lane = tid & 63, w = tid >> 6;
  const int l15 = lane & 15, g = lane >> 4;
  const int obase = w * 128;
  const int n = n0 + l15;
  float xa[8], xc[8];
#pragma unroll
  for (int j=0;j<8;j++){
    xa[j] = xin[(8*g + j)*4096 + n];
    xc[j] = xin[(32 + 8*g + j)*4096 + n];
  }
  union{ i32x4 i; bf16x8 v; } ua, uc;
  ua.i[0]=cvtpk(xa[0],xa[1]); ua.i[1]=cvtpk(xa[2],xa[3]);
  ua.i[2]=cvtpk(xa[4],xa[5]); ua.i[3]=cvtpk(xa[6],xa[7]);
  uc.i[0]=cvtpk(xc[0],xc[1]); uc.i[1]=cvtpk(xc[2],xc[3]);
  uc.i[2]=cvtpk(xc[4],xc[5]); uc.i[3]=cvtpk(xc[6],xc[7]);
  const bf16x8 a0 = ua.v, a1 = uc.v;
  const float* Ws[3] = { Wq, Wk, Wv };
  for (int z=0; z<3; ++z){
    const float* W = Ws[z];
    f32x4 acc[8];
#pragma unroll
    for (int t=0;t<8;t++) acc[t] = (f32x4){0.f,0.f,0.f,0.f};
#pragma unroll
    for (int t=0;t<8;t++){
      const float* brow = W + (size_t)(obase + 16*t + l15)*64;
      bf16x8 b0 = packf8(brow + 8*g);
      bf16x8 b1 = packf8(brow + 32 + 8*g);
      acc[t] = __builtin_amdgcn_mfma_f32_16x16x32_bf16(a0, b0, acc[t], 0,0,0);
      acc[t] = __builtin_amdgcn_mfma_f32_16x16x32_bf16(a1, b1, acc[t], 0,0,0);
    }
    if (z < 2){
#pragma unroll
      for (int hh=0; hh<2; hh++){
        float sfac = (z==0) ? (scale[2*w+hh] * LOG2E) : 1.0f;
#pragma unroll
        for (int r=0;r<4;r++){
          float ss = 0.f;
#pragma unroll
          for (int tt=0;tt<4;tt++){ float v = acc[hh*4+tt][r]; ss += v*v; }
          ss += __shfl_xor(ss, 1); ss += __shfl_xor(ss, 2);
          ss += __shfl_xor(ss, 4); ss += __shfl_xor(ss, 8);
          float inv = sfac / fmaxf(sqrtf(ss), 1e-12f);
#pragma unroll
          for (int tt=0;tt<4;tt++) acc[hh*4+tt][r] *= inv;
        }
      }
      ushort* dst = (z==0) ? q_bf : k_bf;
#pragma unroll
      for (int t=0;t<8;t++){
        int col = obase + 16*t + l15;
#pragma unroll
        for (int r=0;r<4;r++)
          dst[(size_t)(n0 + 4*g + r)*512 + col] = f2bf(acc[t][r]);
      }
    } else {
#pragma unroll
      for (int t=0;t<8;t++){
        int col = obase + 16*t + l15;
        u16x4 vs;
#pragma unroll
        for (int r=0;r<4;r++) vs[r] = f2bf(acc[t][r]);
        *(u16x4*)(vT + (size_t)col*4096 + n0 + 4*g) = vs;
      }
    }
  }
}

// ---------------- D2: flash attention (8 waves x 32 q-rows) + conv ---------
__global__ __launch_bounds__(512) void k_attn_conv(const ushort* __restrict__ q_bf,
    const ushort* __restrict__ k_bf, const ushort* __restrict__ vT,
    ushort* __restrict__ O_part, float* __restrict__ lsum_part, int log2S,
    const float* __restrict__ dw_w, const float* __restrict__ dw_b,
    const float* __restrict__ dw_g, const float* __restrict__ dw_bt,
    const float* __restrict__ dw_m, const float* __restrict__ dw_v,
    ushort* __restrict__ conv_x){
  __shared__ ushort Kt[2][4096];
  __shared__ ushort Vt[2][4096];
  const int S = 1 << log2S;
  const int NA = 128 << log2S;
  const int bid = blockIdx.x;
  const int tid = threadIdx.x;

  if (bid >= NA){
    float* tile = (float*)&Kt[0][0];
    const int d = bid - NA;
    const ushort* src = vT + (size_t)d*4096;
#pragma unroll
    for (int j=0;j<2;j++){
      u16x4 va = *(const u16x4*)(src + tid*4 + 2048*j);
      f32x4 vf;
#pragma unroll
      for (int i=0;i<4;i++) vf[i] = bf2f(va[i]);
      *(f32x4*)&tile[tid*4 + 2048*j] = vf;
    }
    __syncthreads();
    float wv[9];
#pragma unroll
    for (int i=0;i<9;i++) wv[i] = dw_w[d*9+i];
    const float bias = dw_b[d];
    const float bnsc = dw_g[d] * rsqrtf(dw_v[d] + 1e-5f);
    const float bnb  = dw_bt[d] - dw_m[d]*bnsc;
    ushort* dst = conv_x + (size_t)d*4096;
#pragma unroll 4
    for (int i=0;i<8;i++){
      int p = tid + 512*i;
      int y = p >> 6, x = p & 63;
      float acc = 0.f;
#pragma unroll
      for (int ky=0;ky<3;ky++){
        int yy = y + ky - 1;
        if (yy < 0 || yy > 63) continue;
#pragma unroll
        for (int kx=0;kx<3;kx++){
          int xx = x + kx - 1;
          if (xx < 0 || xx > 63) continue;
          acc += wv[ky*3+kx] * tile[yy*64 + xx];
        }
      }
      float cc = (acc + bias)*bnsc + bnb;
      dst[p] = f2bf(gelu_(cc));
    }
    return;
  }
  const int combo = bid & (8*S - 1);
  const int qb = bid >> (3 + log2S);
  const int h = combo >> log2S;
  const int seg = combo & (S - 1);
  const int kv0 = seg * (4096 >> log2S);
  const int iters = (4096 >> log2S) >> 6;   // KVB=64
  const int lane = tid & 63, w = tid >> 6;   // 8 waves
  const int l15 = lane & 15, g = lane >> 4;

  const int lr8 = lane >> 3;
  const int swzc = ((lane & 7) ^ lr8) << 3;
  const ushort* kSrc = k_bf + (size_t)(kv0 + w*8 + lr8)*512 + h*64 + swzc;
  const ushort* vSrc = vT + (size_t)(h*64 + w*8 + lr8)*4096 + kv0 + swzc;
  ushort* klds[2] = { &Kt[0][w*512], &Kt[1][w*512] };
  ushort* vlds[2] = { &Vt[0][w*512], &Vt[1][w*512] };

  const int qrow0 = qb*256 + w*32;
  bf16x8 qa[2][2];
#pragma unroll
  for (int tq=0;tq<2;tq++){
    const ushort* qrow = q_bf + (size_t)(qrow0 + tq*16 + l15)*512 + h*64;
    qa[tq][0] = *(const bf16x8*)(qrow + 8*g);
    qa[tq][1] = *(const bf16x8*)(qrow + 32 + 8*g);
  }
  f32x4 O[2][4];
#pragma unroll
  for (int tq=0;tq<2;tq++)
#pragma unroll
    for (int t=0;t<4;t++) O[tq][t] = (f32x4){0.f,0.f,0.f,0.f};
  float lsum[2] = {0.f,0.f};

  gload16(kSrc, klds[0]);
  gload16(vSrc, vlds[0]);
  asm volatile("s_waitcnt vmcnt(0)" ::: "memory");
  __builtin_amdgcn_s_barrier();

  const int x7 = l15 & 7;
  const int g2 = g >> 1, gh = (g & 1) << 2;

  for (int it = 0; it < iters; ++it){
    const int buf = it & 1;
    if (it + 1 < iters){
      kSrc += 64*512; vSrc += 64;
      gload16(kSrc, klds[buf^1]);
      gload16(vSrc, vlds[buf^1]);
    }
    const ushort* Kb = Kt[buf];
    const ushort* Vb = Vt[buf];
    i32x4 PA[2][2];
#pragma unroll
    for (int s=0;s<4;s++){
      const int rr = 16*s + l15;
      bf16x8 kf0 = *(const bf16x8*)&Kb[rr*64 + ((g     ^ x7) << 3)];
      bf16x8 kf1 = *(const bf16x8*)&Kb[rr*64 + (((4+g) ^ x7) << 3)];
      const int sp = s >> 1, hi = (s & 1) << 1;
#pragma unroll
      for (int tq=0;tq<2;tq++){
        f32x4 st = (f32x4){0.f,0.f,0.f,0.f};
        st = __builtin_amdgcn_mfma_f32_16x16x32_bf16(kf0, qa[tq][0], st, 0,0,0);
        st = __builtin_amdgcn_mfma_f32_16x16x32_bf16(kf1, qa[tq][1], st, 0,0,0);
        float p0 = exp2_(st[0]), p1 = exp2_(st[1]);
        float p2 = exp2_(st[2]), p3 = exp2_(st[3]);
        lsum[tq] += (p0 + p1) + (p2 + p3);
        PA[tq][sp][hi]   = cvtpk(p0, p1);
        PA[tq][sp][hi+1] = cvtpk(p2, p3);
      }
    }
    __builtin_amdgcn_s_setprio(1);
#pragma unroll
    for (int t=0;t<4;t++){
      const int rr = 16*t + l15;
      union { bf16x8 v; i32x2 h2[2]; } u0, u1;
      u0.h2[0] = *(const i32x2*)&Vb[rr*64 + ((g2       ^ x7) << 3) + gh];
      u0.h2[1] = *(const i32x2*)&Vb[rr*64 + (((2 + g2) ^ x7) << 3) + gh];
      u1.h2[0] = *(const i32x2*)&Vb[rr*64 + (((4 + g2) ^ x7) << 3) + gh];
      u1.h2[1] = *(const i32x2*)&Vb[rr*64 + (((6 + g2) ^ x7) << 3) + gh];
#pragma unroll
      for (int tq=0;tq<2;tq++){
        union { i32x4 i; bf16x8 v; } a0, a1;
        a0.i = PA[tq][0]; a1.i = PA[tq][1];
        O[tq][t] = __builtin_amdgcn_mfma_f32_16x16x32_bf16(a0.v, u0.v, O[tq][t], 0,0,0);
        O[tq][t] = __builtin_amdgcn_mfma_f32_16x16x32_bf16(a1.v, u1.v, O[tq][t], 0,0,0);
      }
    }
    __builtin_amdgcn_s_setprio(0);
    asm volatile("s_waitcnt vmcnt(0)" ::: "memory");
    __builtin_amdgcn_s_barrier();
  }
#pragma unroll
  for (int tq=0;tq<2;tq++){
    float ls = lsum[tq];
    ls += __shfl_xor(ls, 16); ls += __shfl_xor(ls, 32);
    if (g == 0)
      lsum_part[((size_t)seg*8 + h)*4096 + qrow0 + tq*16 + l15] = ls;
  }
  ushort* Op = O_part + (size_t)seg*4096*512;
#pragma unroll
  for (int tq=0;tq<2;tq++)
#pragma unroll
    for (int t=0;t<4;t++)
#pragma unroll
      for (int r=0;r<4;r++)
        Op[(size_t)(qrow0 + tq*16 + 4*g + r)*512 + h*64 + 16*t + l15] = f2bf(O[tq][t][r]);
}

// ---------------- D3: combine kv-split partials (templated, vectorized) ----
// 256 blocks x 256 thr, 16 n-rows/block. Thread = (d-chunk of 8, 4 n-rows).
template<int S>
__global__ __launch_bounds__(256) void k_comb_t(const ushort* __restrict__ O_part,
    const float* __restrict__ lsum_part, ushort* __restrict__ att_bf,
    float* __restrict__ pooled){
  __shared__ float Linv[16][8];
  __shared__ float red[4][512];
  const int qbase = blockIdx.x * 16;
  const int tid = threadIdx.x;
  if (tid < 128){
    int q = tid >> 3, h = tid & 7;
    float L = 0.f;
#pragma unroll
    for (int s=0;s<S;s++) L += lsum_part[((size_t)s*8 + h)*4096 + qbase + q];
    Linv[q][h] = 1.0f / L;
  }
  __syncthreads();
  const int ch = tid & 63;        // d-chunk (8 elems)
  const int qg = tid >> 6;        // 0..3
  const int d0 = ch * 8;
  const int hh = ch >> 3;
  float pool[8] = {0.f,0.f,0.f,0.f,0.f,0.f,0.f,0.f};
#pragma unroll
  for (int qq=0; qq<4; qq++){
    const int q = qg*4 + qq;
    const size_t idx = (size_t)(qbase + q)*512 + d0;
    i32x4 seg[S];
#pragma unroll
    for (int s=0;s<S;s++)
      seg[s] = *(const i32x4*)(O_part + (size_t)s*4096*512 + idx);
    float o[8];
#pragma unroll
    for (int j=0;j<8;j++){
      uint pk = ((const uint*)&seg[0])[j>>1];
      o[j] = bf2f((ushort)(pk >> ((j&1)*16)));
    }
#pragma unroll
    for (int s=1;s<S;s++)
#pragma unroll
      for (int j=0;j<8;j++){
        uint pk = ((const uint*)&seg[s])[j>>1];
        o[j] += bf2f((ushort)(pk >> ((j&1)*16)));
      }
    const float li = Linv[q][hh];
    union{ i32x4 i; } w;
#pragma unroll
    for (int j=0;j<8;j++){ o[j] *= li; pool[j] += o[j]; }
    w.i[0]=cvtpk(o[0],o[1]); w.i[1]=cvtpk(o[2],o[3]);
    w.i[2]=cvtpk(o[4],o[5]); w.i[3]=cvtpk(o[6],o[7]);
    *(i32x4*)(att_bf + idx) = w.i;
  }
  *(f32x4*)&red[qg][d0]     = *(f32x4*)&pool[0];
  *(f32x4*)&red[qg][d0 + 4] = *(f32x4*)&pool[4];
  __syncthreads();
  {
    int d = tid;
    float s0 = red[0][d] + red[1][d] + red[2][d] + red[3][d];
    int d2 = tid + 256;
    float s1 = red[0][d2] + red[1][d2] + red[2][d2] + red[3][d2];
    atomicAdd(&pooled[d], s0);
    atomicAdd(&pooled[d2], s1);
  }
}

// ---------------- D4: MLP + conv-transpose + spatial-SE + gate GEMM + embed
// 512 threads (8 waves), K-split 8x64. conv slice transposed in-LDS.
__global__ __launch_bounds__(512) void k_final(const ushort* __restrict__ att_bf,
    const ushort* __restrict__ conv_x, const ushort* __restrict__ si_w1b,
    const float* __restrict__ si_b1, const float* __restrict__ si_g,
    const float* __restrict__ si_bt, const float* __restrict__ si_m,
    const float* __restrict__ si_v, const float* __restrict__ si_w2,
    const float* __restrict__ si_b2,
    const float* __restrict__ pooled, const float* __restrict__ ci_w1,
    const float* __restrict__ ci_b1, const float* __restrict__ ci_w2,
    const float* __restrict__ ci_b2,
    const ushort* __restrict__ Woutb, const float* __restrict__ bout,
    const float* __restrict__ embed, float* __restrict__ out){
  __shared__ ushort ct[16*520];           // [n-local][d], padded rows
  __shared__ float pl[512];
  __shared__ float h1[128];
  __shared__ float scm[512];
  __shared__ f32x4 part2[8][2][64];
  __shared__ float smv[16];
  __shared__ f32x4 part[8][4][64];
  const int tid = threadIdx.x;
  const int lane = tid & 63, w = tid >> 6;       // 8 waves
  const int l15 = lane & 15, g = lane >> 4;
  const int n0 = blockIdx.x * 16;
  const int rowA = n0 + l15;
  // stage: pooled/4096 + conv slice transpose (thread t = d-row t)
  pl[tid] = pooled[tid] * (1.0f/4096.0f);
  {
    const ushort* s = conv_x + (size_t)tid*4096 + n0;
    union{ i32x4 q[2]; ushort e[16]; } u;
    u.q[0] = *(const i32x4*)s;
    u.q[1] = *(const i32x4*)(s + 8);
#pragma unroll
    for (int j=0;j<16;j++) ct[j*520 + tid] = u.e[j];
  }
  // att fragments (K chunk = w*64)
  bf16x8 at8[2];
#pragma unroll
  for (int kk=0;kk<2;kk++){
    int k0 = w*64 + kk*32 + 8*g;
    at8[kk] = *(const bf16x8*)(att_bf + (size_t)rowA*512 + k0);
  }
  __syncthreads();
  // channel MLP layer 1: all 512 threads, e = tid>>2, quarter-K + 2 shfl
  {
    int e = tid >> 2;
    int base = (tid & 3) * 128;
    float acc = 0.f;
    const float* wr = ci_w1 + (size_t)e*512 + base;
#pragma unroll 8
    for (int c=0;c<128;c++) acc += wr[c]*pl[base + c];
    acc += __shfl_xor(acc, 1);
    acc += __shfl_xor(acc, 2);
    if (!(tid & 3)) h1[e] = gelu_(acc + ci_b1[e]);
  }
  // conv fragments from transposed LDS
  bf16x8 cn8[2];
#pragma unroll
  for (int kk=0;kk<2;kk++){
    int k0 = w*64 + kk*32 + 8*g;
    cn8[kk] = *(const bf16x8*)&ct[l15*520 + k0];
  }
  __syncthreads();
  // channel MLP layer 2: d = tid (512)
  {
    float acc = ci_b2[tid];
    const float* wr = ci_w2 + (size_t)tid*128;
#pragma unroll 8
    for (int e=0;e<128;e++) acc += wr[e]*h1[e];
    scm[tid] = sigmoid_(acc);
  }
  // spatial: s1 = conv . si_w1^T (32 e), K-split by wave
  f32x4 a2[2];
  a2[0] = (f32x4){0.f,0.f,0.f,0.f};
  a2[1] = (f32x4){0.f,0.f,0.f,0.f};
#pragma unroll
  for (int kk=0;kk<2;kk++){
    int k0 = w*64 + kk*32 + 8*g;
#pragma unroll
    for (int t=0;t<2;t++){
      bf16x8 b = *(const bf16x8*)(si_w1b + (size_t)(16*t + l15)*512 + k0);
      a2[t] = __builtin_amdgcn_mfma_f32_16x16x32_bf16(cn8[kk], b, a2[t], 0,0,0);
    }
  }
  part2[w][0][lane] = a2[0];
  part2[w][1][lane] = a2[1];
  __syncthreads();
  if (w == 0){
    float rowv[4] = {0.f,0.f,0.f,0.f};
#pragma unroll
    for (int t=0;t<2;t++){
      f32x4 s4 = part2[0][t][lane];
#pragma unroll
      for (int ww=1;ww<8;ww++) s4 = s4 + part2[ww][t][lane];
      int e = 16*t + l15;
      float s = si_g[e] * rsqrtf(si_v[e] + 1e-5f);
      float b1 = si_b1[e] - si_m[e];
      float bt = si_bt[e];
      float w2e = si_w2[e];
#pragma unroll
      for (int r=0;r<4;r++){
        float v = (s4[r] + b1)*s + bt;
        rowv[r] += w2e * gelu_(v);
      }
    }
    float sb2 = si_b2[0];
#pragma unroll
    for (int r=0;r<4;r++){
      float v = rowv[r];
      v += __shfl_xor(v,1); v += __shfl_xor(v,2);
      v += __shfl_xor(v,4); v += __shfl_xor(v,8);
      if (l15 == 0) smv[4*g + r] = sigmoid_(v + sb2);
    }
  }
  __syncthreads();
  const float srow = smv[l15];
  // gate + output GEMM (K chunk = w*64)
  f32x4 acc[4];
#pragma unroll
  for (int t=0;t<4;t++) acc[t] = (f32x4){0.f,0.f,0.f,0.f};
#pragma unroll
  for (int kk=0;kk<2;kk++){
    int k0 = w*64 + kk*32 + 8*g;
    bf16x8 af;
#pragma unroll
    for (int i=0;i<8;i++){
      int d = k0 + i;
      float zv = bf2f((ushort)at8[kk][i]) * srow + bf2f((ushort)cn8[kk][i]) * scm[d];
      af[i] = (short)f2bf(zv);
    }
#pragma unroll
    for (int t=0;t<4;t++){
      bf16x8 bf8 = *(const bf16x8*)(Woutb + (size_t)(16*t+l15)*512 + k0);
      acc[t] = __builtin_amdgcn_mfma_f32_16x16x32_bf16(af, bf8, acc[t], 0,0,0);
    }
  }
#pragma unroll
  for (int t=0;t<4;t++) part[w][t][lane] = acc[t];
  __syncthreads();
  if (w < 4){
    f32x4 s4 = part[0][w][lane];
#pragma unroll
    for (int ww=1;ww<8;ww++) s4 = s4 + part[ww][w][lane];
    int o = 16*w + l15;
    float bo = bout[o];
#pragma unroll
    for (int r=0;r<4;r++){
      int row = n0 + 4*g + r;
      size_t idx = (size_t)row*64 + o;
      out[idx] = s4[r] + bo + embed[idx];
    }
  }
}

extern "C" void kernel_launch(void* const* d_in, const int* in_sizes, int n_in,
                              void* d_out, int out_size, void* d_ws, size_t ws_size,
                              hipStream_t stream){
  (void)in_sizes; (void)n_in; (void)out_size;
  const float* x_in  = (const float*)d_in[0];
  const float* Wq    = (const float*)d_in[1];
  const float* Wk    = (const float*)d_in[2];
  const float* Wv    = (const float*)d_in[3];
  const float* scale = (const float*)d_in[4];
  const float* Wout  = (const float*)d_in[5];
  const float* bout  = (const float*)d_in[6];
  const float* dw_w  = (const float*)d_in[7];
  const float* dw_b  = (const float*)d_in[8];
  const float* dw_g  = (const float*)d_in[9];
  const float* dw_bt = (const float*)d_in[10];
  const float* dw_m  = (const float*)d_in[11];
  const float* dw_v  = (const float*)d_in[12];
  const float* ci_w1 = (const float*)d_in[13];
  const float* ci_b1 = (const float*)d_in[14];
  const float* ci_w2 = (const float*)d_in[15];
  const float* ci_b2 = (const float*)d_in[16];
  const float* si_w1 = (const float*)d_in[17];
  const float* si_b1 = (const float*)d_in[18];
  const float* si_g  = (const float*)d_in[19];
  const float* si_bt = (const float*)d_in[20];
  const float* si_m  = (const float*)d_in[21];
  const float* si_v  = (const float*)d_in[22];
  const float* si_w2 = (const float*)d_in[23];
  const float* si_b2 = (const float*)d_in[24];
  const float* pe_w1 = (const float*)d_in[25];
  const float* pe_w2 = (const float*)d_in[26];
  float* out = (float*)d_out;

  char* p = (char*)d_ws;
  auto alloc = [&](size_t bytes)->char*{
    char* r = p; p += (bytes + 255) & ~(size_t)255; return r;
  };
  ushort* q_bf    = (ushort*)alloc((size_t)4096*512*2);
  ushort* k_bf    = (ushort*)alloc((size_t)4096*512*2);
  ushort* vTb     = (ushort*)alloc((size_t)512*4096*2);
  ushort* att_bf  = (ushort*)alloc((size_t)4096*512*2);
  ushort* conv_x  = (ushort*)alloc((size_t)512*4096*2);
  ushort* Woutb   = (ushort*)alloc((size_t)32768*2);
  ushort* si_w1b  = (ushort*)alloc((size_t)16384*2);
  float*  embed   = (float*) alloc((size_t)64*4096*4);
  float*  lsum_p  = (float*) alloc((size_t)8*8*4096*4);
  float*  pooled  = (float*) alloc(512*4);
  size_t used = (size_t)(p - (char*)d_ws);
  size_t segBytes = (size_t)4096*512*2 + 256;   // bf16 partials
  size_t avail = (ws_size > used) ? (ws_size - used) : 0;
  int log2S = 2;
  if (avail < 4*segBytes) log2S = 1;
  if (avail < 2*segBytes) log2S = 0;
  int S = 1 << log2S;
  ushort* O_part = (ushort*)alloc((size_t)S*segBytes);
  int NA = 128 << log2S;

  k_qkv<<<dim3(256,2), 256, 0, stream>>>(x_in, Wq, Wk, Wv, scale, q_bf, k_bf, vTb,
                                         pe_w1, pe_w2, embed, Wout, si_w1,
                                         Woutb, si_w1b, pooled);
  k_attn_conv<<<NA + 512, 512, 0, stream>>>(q_bf, k_bf, vTb, O_part, lsum_p, log2S,
                                            dw_w, dw_b, dw_g, dw_bt, dw_m, dw_v,
                                            conv_x);
  if (log2S == 2)
    k_comb_t<4><<<256, 256, 0, stream>>>(O_part, lsum_p, att_bf, pooled);
  else if (log2S == 1)
    k_comb_t<2><<<256, 256, 0, stream>>>(O_part, lsum_p, att_bf, pooled);
  else
    k_comb_t<1><<<256, 256, 0, stream>>>(O_part, lsum_p, att_bf, pooled);
  k_final<<<256, 512, 0, stream>>>(att_bf, conv_x, si_w1b, si_b1, si_g, si_bt,
                                   si_m, si_v, si_w2, si_b2,
                                   pooled, ci_w1, ci_b1, ci_w2, ci_b2,
                                   Woutb, bout, embed, out);
}

// Round 21
// 99.438 us; speedup vs baseline: 1.1264x; 1.0135x over previous
//
#include <hip/hip_runtime.h>

// MultiAttention fused pipeline for MI355X (gfx950).
// B=1, C=64, H=W=64 (N=4096), NH=8, DK=64, D=512.
// NOTE (r16 lesson): last-block + __threadfence cross-block signalling costs
// ~70us on MI355X (per-XCD L2 writeback) -- never use it here.
// NOTE (r19 lesson): KVB=128 (64KB LDS dbuf) drops occupancy 34->19% and
// regresses attn 48->60us; KVB=64 is optimal for the 8-wave structure.

#define LOG2E 1.442695040888963f

typedef __attribute__((ext_vector_type(8))) short bf16x8;
typedef __attribute__((ext_vector_type(4))) float f32x4;
typedef __attribute__((ext_vector_type(4))) int i32x4;
typedef __attribute__((ext_vector_type(2))) int i32x2;
typedef __attribute__((ext_vector_type(4))) ushort u16x4;

__device__ __forceinline__ ushort f2bf(float x){
  uint u = __float_as_uint(x);
  u += 0x7fffu + ((u >> 16) & 1u);   // round-to-nearest-even
  return (ushort)(u >> 16);
}
__device__ __forceinline__ float bf2f(ushort h){
  return __uint_as_float(((uint)h) << 16);
}
__device__ __forceinline__ float gelu_(float x){
  return 0.5f * x * (1.0f + erff(x * 0.70710678118654752f));
}
__device__ __forceinline__ float sigmoid_(float x){
  return 1.0f / (1.0f + __expf(-x));
}
__device__ __forceinline__ float exp2_(float x){
  float r; asm("v_exp_f32 %0, %1" : "=v"(r) : "v"(x)); return r;
}
__device__ __forceinline__ int cvtpk(float lo, float hi){
  int r; asm("v_cvt_pk_bf16_f32 %0, %1, %2" : "=v"(r) : "v"(lo), "v"(hi)); return r;
}
__device__ __forceinline__ bf16x8 packf8(const float* s){
  f32x4 x0 = *(const f32x4*)s;
  f32x4 x1 = *(const f32x4*)(s+4);
  union{ i32x4 i; bf16x8 v; } u;
  u.i[0]=cvtpk(x0[0],x0[1]); u.i[1]=cvtpk(x0[2],x0[3]);
  u.i[2]=cvtpk(x1[0],x1[1]); u.i[3]=cvtpk(x1[2],x1[3]);
  return u.v;
}
// async global->LDS, 16B per lane; LDS dest = wave-uniform base + lane*16
__device__ __forceinline__ void gload16(const ushort* g, ushort* l){
  __builtin_amdgcn_global_load_lds(
    (const __attribute__((address_space(1))) uint*)(const void*)g,
    (__attribute__((address_space(3))) uint*)(void*)l, 16, 0, 0);
}

// ---------------- D0: QKV weight pre-conversion (f32 -> bf16, once) --------
// 96 blocks x 256 thr x 4 elems: Wq (blocks 0..31), Wk (32..63), Wv (64..95).
__global__ __launch_bounds__(256) void k_wcvt(const float* __restrict__ Wq,
    const float* __restrict__ Wk, const float* __restrict__ Wv,
    ushort* __restrict__ Wqb, ushort* __restrict__ Wkb, ushort* __restrict__ Wvb){
  const int grp = blockIdx.x >> 5;
  const float* src = (grp==0) ? Wq : (grp==1) ? Wk : Wv;
  ushort* dst = (grp==0) ? Wqb : (grp==1) ? Wkb : Wvb;
  const int idx = ((blockIdx.x & 31)*256 + threadIdx.x) * 4;
  f32x4 v = *(const f32x4*)(src + idx);
  union{ i32x2 i; u16x4 u; } o;
  o.i[0] = cvtpk(v[0], v[1]);
  o.i[1] = cvtpk(v[2], v[3]);
  *(u16x4*)(dst + idx) = o.u;
}

// ---------------- D1: fused QKV projection (y=0) ; pe-branch + wprep (y=1) -
__global__ __launch_bounds__(256) void k_qkv(const float* __restrict__ xin,
    const ushort* __restrict__ Wqb, const ushort* __restrict__ Wkb,
    const ushort* __restrict__ Wvb, const float* __restrict__ scale,
    ushort* __restrict__ q_bf, ushort* __restrict__ k_bf, ushort* __restrict__ vT,
    const float* __restrict__ pe_w1, const float* __restrict__ pe_w2,
    float* __restrict__ embed, const float* __restrict__ Wout,
    const float* __restrict__ si_w1, ushort* __restrict__ Woutb,
    ushort* __restrict__ si_w1b, float* __restrict__ pooled){
  __shared__ float t0[20*64];
  __shared__ float t1[18*64];
  const int tid = threadIdx.x;
  if (blockIdx.y == 1){
    if (tid < 192){
      int i = blockIdx.x*192 + tid;
      if (i < 32768) Woutb[i] = f2bf(Wout[i]);
      else           si_w1b[i - 32768] = f2bf(si_w1[i - 32768]);
    }
    if (blockIdx.x == 0){ pooled[tid] = 0.f; pooled[tid+256] = 0.f; }
    const int c = blockIdx.x >> 2;
    const int r0 = (blockIdx.x & 3) * 16;
    const float* src = xin + (size_t)c*4096;
#pragma unroll
    for (int i=0;i<5;i++){
      int idx = tid + 256*i;
      if (idx < 1280){
        int lr = idx >> 6, x = idx & 63;
        int gr = r0 - 2 + lr;
        t0[idx] = (gr >= 0 && gr < 64) ? src[gr*64 + x] : 0.f;
      }
    }
    __syncthreads();
    float w1[9], w2[9];
#pragma unroll
    for (int i=0;i<9;i++){ w1[i] = pe_w1[c*9+i]; w2[i] = pe_w2[c*9+i]; }
#pragma unroll
    for (int i=0;i<5;i++){
      int idx = tid + 256*i;
      if (idx < 1152){
        int lr = idx >> 6, x = idx & 63;
        int gr = r0 - 1 + lr;
        float acc = 0.f;
        if (gr >= 0 && gr < 64){
#pragma unroll
          for (int ky=0;ky<3;ky++){
            int gy = gr + ky - 1;
            if (gy < 0 || gy > 63) continue;
#pragma unroll
            for (int kx=0;kx<3;kx++){
              int xx = x + kx - 1;
              if (xx < 0 || xx > 63) continue;
              acc += w1[ky*3+kx] * t0[(lr + ky)*64 + xx];
            }
          }
          acc = gelu_(acc);
        }
        t1[idx] = acc;
      }
    }
    __syncthreads();
    float* dst = embed + (size_t)c*4096;
#pragma unroll
    for (int i=0;i<4;i++){
      int idx = tid + 256*i;
      int lr = idx >> 6, x = idx & 63;
      int gr = r0 + lr;
      float acc = 0.f;
#pragma unroll
      for (int ky=0;ky<3;ky++){
        int gy = gr + ky - 1;
        if (gy < 0 || gy > 63) continue;
#pragma unroll
        for (int kx=0;kx<3;kx++){
          int xx = x + kx - 1;
          if (xx < 0 || xx > 63) continue;
          acc += w2[ky*3+kx] * t1[(lr + ky)*64 + xx];
        }
      }
      dst[gr*64 + x] = acc;
    }
    return;
  }
  // ---- fused QKV: one block does q, k, v for its 16-row strip (A reused) --
  const int n0 = blockIdx.x * 16;
  const int lane = tid & 63, w = tid >> 6;
  const int l15 = lane & 15, g = lane >> 4;
  const int obase = w * 128;
  const int n = n0 + l15;
  float xa[8], xc[8];
#pragma unroll
  for (int j=0;j<8;j++){
    xa[j] = xin[(8*g + j)*4096 + n];
    xc[j] = xin[(32 + 8*g + j)*4096 + n];
  }
  union{ i32x4 i; bf16x8 v; } ua, uc;
  ua.i[0]=cvtpk(xa[0],xa[1]); ua.i[1]=cvtpk(xa[2],xa[3]);
  ua.i[2]=cvtpk(xa[4],xa[5]); ua.i[3]=cvtpk(xa[6],xa[7]);
  uc.i[0]=cvtpk(xc[0],xc[1]); uc.i[1]=cvtpk(xc[2],xc[3]);
  uc.i[2]=cvtpk(xc[4],xc[5]); uc.i[3]=cvtpk(xc[6],xc[7]);
  const bf16x8 a0 = ua.v, a1 = uc.v;
  const ushort* Ws[3] = { Wqb, Wkb, Wvb };
  for (int z=0; z<3; ++z){
    const ushort* W = Ws[z];
    f32x4 acc[8];
#pragma unroll
    for (int t=0;t<8;t++) acc[t] = (f32x4){0.f,0.f,0.f,0.f};
#pragma unroll
    for (int t=0;t<8;t++){
      const ushort* brow = W + (size_t)(obase + 16*t + l15)*64;
      bf16x8 b0 = *(const bf16x8*)(brow + 8*g);
      bf16x8 b1 = *(const bf16x8*)(brow + 32 + 8*g);
      acc[t] = __builtin_amdgcn_mfma_f32_16x16x32_bf16(a0, b0, acc[t], 0,0,0);
      acc[t] = __builtin_amdgcn_mfma_f32_16x16x32_bf16(a1, b1, acc[t], 0,0,0);
    }
    if (z < 2){
#pragma unroll
      for (int hh=0; hh<2; hh++){
        float sfac = (z==0) ? (scale[2*w+hh] * LOG2E) : 1.0f;
#pragma unroll
        for (int r=0;r<4;r++){
          float ss = 0.f;
#pragma unroll
          for (int tt=0;tt<4;tt++){ float v = acc[hh*4+tt][r]; ss += v*v; }
          ss += __shfl_xor(ss, 1); ss += __shfl_xor(ss, 2);
          ss += __shfl_xor(ss, 4); ss += __shfl_xor(ss, 8);
          float inv = sfac / fmaxf(sqrtf(ss), 1e-12f);
#pragma unroll
          for (int tt=0;tt<4;tt++) acc[hh*4+tt][r] *= inv;
        }
      }
      ushort* dst = (z==0) ? q_bf : k_bf;
#pragma unroll
      for (int t=0;t<8;t++){
        int col = obase + 16*t + l15;
#pragma unroll
        for (int r=0;r<4;r++)
          dst[(size_t)(n0 + 4*g + r)*512 + col] = f2bf(acc[t][r]);
      }
    } else {
#pragma unroll
      for (int t=0;t<8;t++){
        int col = obase + 16*t + l15;
        u16x4 vs;
#pragma unroll
        for (int r=0;r<4;r++) vs[r] = f2bf(acc[t][r]);
        *(u16x4*)(vT + (size_t)col*4096 + n0 + 4*g) = vs;
      }
    }
  }
}

// ---------------- D2: flash attention (8 waves x 32 q-rows) + conv ---------
__global__ __launch_bounds__(512) void k_attn_conv(const ushort* __restrict__ q_bf,
    const ushort* __restrict__ k_bf, const ushort* __restrict__ vT,
    ushort* __restrict__ O_part, float* __restrict__ lsum_part, int log2S,
    const float* __restrict__ dw_w, const float* __restrict__ dw_b,
    const float* __restrict__ dw_g, const float* __restrict__ dw_bt,
    const float* __restrict__ dw_m, const float* __restrict__ dw_v,
    ushort* __restrict__ conv_x){
  __shared__ ushort Kt[2][4096];
  __shared__ ushort Vt[2][4096];
  const int S = 1 << log2S;
  const int NA = 128 << log2S;
  const int bid = blockIdx.x;
  const int tid = threadIdx.x;

  if (bid >= NA){
    float* tile = (float*)&Kt[0][0];
    const int d = bid - NA;
    const ushort* src = vT + (size_t)d*4096;
#pragma unroll
    for (int j=0;j<2;j++){
      u16x4 va = *(const u16x4*)(src + tid*4 + 2048*j);
      f32x4 vf;
#pragma unroll
      for (int i=0;i<4;i++) vf[i] = bf2f(va[i]);
      *(f32x4*)&tile[tid*4 + 2048*j] = vf;
    }
    __syncthreads();
    float wv[9];
#pragma unroll
    for (int i=0;i<9;i++) wv[i] = dw_w[d*9+i];
    const float bias = dw_b[d];
    const float bnsc = dw_g[d] * rsqrtf(dw_v[d] + 1e-5f);
    const float bnb  = dw_bt[d] - dw_m[d]*bnsc;
    ushort* dst = conv_x + (size_t)d*4096;
#pragma unroll 4
    for (int i=0;i<8;i++){
      int p = tid + 512*i;
      int y = p >> 6, x = p & 63;
      float acc = 0.f;
#pragma unroll
      for (int ky=0;ky<3;ky++){
        int yy = y + ky - 1;
        if (yy < 0 || yy > 63) continue;
#pragma unroll
        for (int kx=0;kx<3;kx++){
          int xx = x + kx - 1;
          if (xx < 0 || xx > 63) continue;
          acc += wv[ky*3+kx] * tile[yy*64 + xx];
        }
      }
      float cc = (acc + bias)*bnsc + bnb;
      dst[p] = f2bf(gelu_(cc));
    }
    return;
  }
  const int combo = bid & (8*S - 1);
  const int qb = bid >> (3 + log2S);
  const int h = combo >> log2S;
  const int seg = combo & (S - 1);
  const int kv0 = seg * (4096 >> log2S);
  const int iters = (4096 >> log2S) >> 6;   // KVB=64
  const int lane = tid & 63, w = tid >> 6;   // 8 waves
  const int l15 = lane & 15, g = lane >> 4;

  const int lr8 = lane >> 3;
  const int swzc = ((lane & 7) ^ lr8) << 3;
  const ushort* kSrc = k_bf + (size_t)(kv0 + w*8 + lr8)*512 + h*64 + swzc;
  const ushort* vSrc = vT + (size_t)(h*64 + w*8 + lr8)*4096 + kv0 + swzc;
  ushort* klds[2] = { &Kt[0][w*512], &Kt[1][w*512] };
  ushort* vlds[2] = { &Vt[0][w*512], &Vt[1][w*512] };

  const int qrow0 = qb*256 + w*32;
  bf16x8 qa[2][2];
#pragma unroll
  for (int tq=0;tq<2;tq++){
    const ushort* qrow = q_bf + (size_t)(qrow0 + tq*16 + l15)*512 + h*64;
    qa[tq][0] = *(const bf16x8*)(qrow + 8*g);
    qa[tq][1] = *(const bf16x8*)(qrow + 32 + 8*g);
  }
  f32x4 O[2][4];
#pragma unroll
  for (int tq=0;tq<2;tq++)
#pragma unroll
    for (int t=0;t<4;t++) O[tq][t] = (f32x4){0.f,0.f,0.f,0.f};
  float lsum[2] = {0.f,0.f};

  gload16(kSrc, klds[0]);
  gload16(vSrc, vlds[0]);
  asm volatile("s_waitcnt vmcnt(0)" ::: "memory");
  __builtin_amdgcn_s_barrier();

  const int x7 = l15 & 7;
  const int g2 = g >> 1, gh = (g & 1) << 2;

  for (int it = 0; it < iters; ++it){
    const int buf = it & 1;
    if (it + 1 < iters){
      kSrc += 64*512; vSrc += 64;
      gload16(kSrc, klds[buf^1]);
      gload16(vSrc, vlds[buf^1]);
    }
    const ushort* Kb = Kt[buf];
    const ushort* Vb = Vt[buf];
    i32x4 PA[2][2];
#pragma unroll
    for (int s=0;s<4;s++){
      const int rr = 16*s + l15;
      bf16x8 kf0 = *(const bf16x8*)&Kb[rr*64 + ((g     ^ x7) << 3)];
      bf16x8 kf1 = *(const bf16x8*)&Kb[rr*64 + (((4+g) ^ x7) << 3)];
      const int sp = s >> 1, hi = (s & 1) << 1;
#pragma unroll
      for (int tq=0;tq<2;tq++){
        f32x4 st = (f32x4){0.f,0.f,0.f,0.f};
        st = __builtin_amdgcn_mfma_f32_16x16x32_bf16(kf0, qa[tq][0], st, 0,0,0);
        st = __builtin_amdgcn_mfma_f32_16x16x32_bf16(kf1, qa[tq][1], st, 0,0,0);
        float p0 = exp2_(st[0]), p1 = exp2_(st[1]);
        float p2 = exp2_(st[2]), p3 = exp2_(st[3]);
        lsum[tq] += (p0 + p1) + (p2 + p3);
        PA[tq][sp][hi]   = cvtpk(p0, p1);
        PA[tq][sp][hi+1] = cvtpk(p2, p3);
      }
    }
    __builtin_amdgcn_s_setprio(1);
#pragma unroll
    for (int t=0;t<4;t++){
      const int rr = 16*t + l15;
      union { bf16x8 v; i32x2 h2[2]; } u0, u1;
      u0.h2[0] = *(const i32x2*)&Vb[rr*64 + ((g2       ^ x7) << 3) + gh];
      u0.h2[1] = *(const i32x2*)&Vb[rr*64 + (((2 + g2) ^ x7) << 3) + gh];
      u1.h2[0] = *(const i32x2*)&Vb[rr*64 + (((4 + g2) ^ x7) << 3) + gh];
      u1.h2[1] = *(const i32x2*)&Vb[rr*64 + (((6 + g2) ^ x7) << 3) + gh];
#pragma unroll
      for (int tq=0;tq<2;tq++){
        union { i32x4 i; bf16x8 v; } a0, a1;
        a0.i = PA[tq][0]; a1.i = PA[tq][1];
        O[tq][t] = __builtin_amdgcn_mfma_f32_16x16x32_bf16(a0.v, u0.v, O[tq][t], 0,0,0);
        O[tq][t] = __builtin_amdgcn_mfma_f32_16x16x32_bf16(a1.v, u1.v, O[tq][t], 0,0,0);
      }
    }
    __builtin_amdgcn_s_setprio(0);
    asm volatile("s_waitcnt vmcnt(0)" ::: "memory");
    __builtin_amdgcn_s_barrier();
  }
#pragma unroll
  for (int tq=0;tq<2;tq++){
    float ls = lsum[tq];
    ls += __shfl_xor(ls, 16); ls += __shfl_xor(ls, 32);
    if (g == 0)
      lsum_part[((size_t)seg*8 + h)*4096 + qrow0 + tq*16 + l15] = ls;
  }
  ushort* Op = O_part + (size_t)seg*4096*512;
#pragma unroll
  for (int tq=0;tq<2;tq++)
#pragma unroll
    for (int t=0;t<4;t++)
#pragma unroll
      for (int r=0;r<4;r++)
        Op[(size_t)(qrow0 + tq*16 + 4*g + r)*512 + h*64 + 16*t + l15] = f2bf(O[tq][t][r]);
}

// ---------------- D3: combine kv-split partials (templated, vectorized) ----
// 256 blocks x 256 thr, 16 n-rows/block. Thread = (d-chunk of 8, 4 n-rows).
template<int S>
__global__ __launch_bounds__(256) void k_comb_t(const ushort* __restrict__ O_part,
    const float* __restrict__ lsum_part, ushort* __restrict__ att_bf,
    float* __restrict__ pooled){
  __shared__ float Linv[16][8];
  __shared__ float red[4][512];
  const int qbase = blockIdx.x * 16;
  const int tid = threadIdx.x;
  if (tid < 128){
    int q = tid >> 3, h = tid & 7;
    float L = 0.f;
#pragma unroll
    for (int s=0;s<S;s++) L += lsum_part[((size_t)s*8 + h)*4096 + qbase + q];
    Linv[q][h] = 1.0f / L;
  }
  __syncthreads();
  const int ch = tid & 63;        // d-chunk (8 elems)
  const int qg = tid >> 6;        // 0..3
  const int d0 = ch * 8;
  const int hh = ch >> 3;
  float pool[8] = {0.f,0.f,0.f,0.f,0.f,0.f,0.f,0.f};
#pragma unroll
  for (int qq=0; qq<4; qq++){
    const int q = qg*4 + qq;
    const size_t idx = (size_t)(qbase + q)*512 + d0;
    i32x4 seg[S];
#pragma unroll
    for (int s=0;s<S;s++)
      seg[s] = *(const i32x4*)(O_part + (size_t)s*4096*512 + idx);
    float o[8];
#pragma unroll
    for (int j=0;j<8;j++){
      uint pk = ((const uint*)&seg[0])[j>>1];
      o[j] = bf2f((ushort)(pk >> ((j&1)*16)));
    }
#pragma unroll
    for (int s=1;s<S;s++)
#pragma unroll
      for (int j=0;j<8;j++){
        uint pk = ((const uint*)&seg[s])[j>>1];
        o[j] += bf2f((ushort)(pk >> ((j&1)*16)));
      }
    const float li = Linv[q][hh];
    union{ i32x4 i; } w;
#pragma unroll
    for (int j=0;j<8;j++){ o[j] *= li; pool[j] += o[j]; }
    w.i[0]=cvtpk(o[0],o[1]); w.i[1]=cvtpk(o[2],o[3]);
    w.i[2]=cvtpk(o[4],o[5]); w.i[3]=cvtpk(o[6],o[7]);
    *(i32x4*)(att_bf + idx) = w.i;
  }
  *(f32x4*)&red[qg][d0]     = *(f32x4*)&pool[0];
  *(f32x4*)&red[qg][d0 + 4] = *(f32x4*)&pool[4];
  __syncthreads();
  {
    int d = tid;
    float s0 = red[0][d] + red[1][d] + red[2][d] + red[3][d];
    int d2 = tid + 256;
    float s1 = red[0][d2] + red[1][d2] + red[2][d2] + red[3][d2];
    atomicAdd(&pooled[d], s0);
    atomicAdd(&pooled[d2], s1);
  }
}

// ---------------- D4: MLP + conv-transpose + spatial-SE + gate GEMM + embed
// 512 threads (8 waves), K-split 8x64. conv slice transposed in-LDS.
__global__ __launch_bounds__(512) void k_final(const ushort* __restrict__ att_bf,
    const ushort* __restrict__ conv_x, const ushort* __restrict__ si_w1b,
    const float* __restrict__ si_b1, const float* __restrict__ si_g,
    const float* __restrict__ si_bt, const float* __restrict__ si_m,
    const float* __restrict__ si_v, const float* __restrict__ si_w2,
    const float* __restrict__ si_b2,
    const float* __restrict__ pooled, const float* __restrict__ ci_w1,
    const float* __restrict__ ci_b1, const float* __restrict__ ci_w2,
    const float* __restrict__ ci_b2,
    const ushort* __restrict__ Woutb, const float* __restrict__ bout,
    const float* __restrict__ embed, float* __restrict__ out){
  __shared__ ushort ct[16*520];           // [n-local][d], padded rows
  __shared__ float pl[512];
  __shared__ float h1[128];
  __shared__ float scm[512];
  __shared__ f32x4 part2[8][2][64];
  __shared__ float smv[16];
  __shared__ f32x4 part[8][4][64];
  const int tid = threadIdx.x;
  const int lane = tid & 63, w = tid >> 6;       // 8 waves
  const int l15 = lane & 15, g = lane >> 4;
  const int n0 = blockIdx.x * 16;
  const int rowA = n0 + l15;
  // stage: pooled/4096 + conv slice transpose (thread t = d-row t)
  pl[tid] = pooled[tid] * (1.0f/4096.0f);
  {
    const ushort* s = conv_x + (size_t)tid*4096 + n0;
    union{ i32x4 q[2]; ushort e[16]; } u;
    u.q[0] = *(const i32x4*)s;
    u.q[1] = *(const i32x4*)(s + 8);
#pragma unroll
    for (int j=0;j<16;j++) ct[j*520 + tid] = u.e[j];
  }
  // att fragments (K chunk = w*64)
  bf16x8 at8[2];
#pragma unroll
  for (int kk=0;kk<2;kk++){
    int k0 = w*64 + kk*32 + 8*g;
    at8[kk] = *(const bf16x8*)(att_bf + (size_t)rowA*512 + k0);
  }
  __syncthreads();
  // channel MLP layer 1: all 512 threads, e = tid>>2, quarter-K + 2 shfl
  {
    int e = tid >> 2;
    int base = (tid & 3) * 128;
    float acc = 0.f;
    const float* wr = ci_w1 + (size_t)e*512 + base;
#pragma unroll 8
    for (int c=0;c<128;c++) acc += wr[c]*pl[base + c];
    acc += __shfl_xor(acc, 1);
    acc += __shfl_xor(acc, 2);
    if (!(tid & 3)) h1[e] = gelu_(acc + ci_b1[e]);
  }
  // conv fragments from transposed LDS
  bf16x8 cn8[2];
#pragma unroll
  for (int kk=0;kk<2;kk++){
    int k0 = w*64 + kk*32 + 8*g;
    cn8[kk] = *(const bf16x8*)&ct[l15*520 + k0];
  }
  __syncthreads();
  // channel MLP layer 2: d = tid (512)
  {
    float acc = ci_b2[tid];
    const float* wr = ci_w2 + (size_t)tid*128;
#pragma unroll 8
    for (int e=0;e<128;e++) acc += wr[e]*h1[e];
    scm[tid] = sigmoid_(acc);
  }
  // spatial: s1 = conv . si_w1^T (32 e), K-split by wave
  f32x4 a2[2];
  a2[0] = (f32x4){0.f,0.f,0.f,0.f};
  a2[1] = (f32x4){0.f,0.f,0.f,0.f};
#pragma unroll
  for (int kk=0;kk<2;kk++){
    int k0 = w*64 + kk*32 + 8*g;
#pragma unroll
    for (int t=0;t<2;t++){
      bf16x8 b = *(const bf16x8*)(si_w1b + (size_t)(16*t + l15)*512 + k0);
      a2[t] = __builtin_amdgcn_mfma_f32_16x16x32_bf16(cn8[kk], b, a2[t], 0,0,0);
    }
  }
  part2[w][0][lane] = a2[0];
  part2[w][1][lane] = a2[1];
  __syncthreads();
  if (w == 0){
    float rowv[4] = {0.f,0.f,0.f,0.f};
#pragma unroll
    for (int t=0;t<2;t++){
      f32x4 s4 = part2[0][t][lane];
#pragma unroll
      for (int ww=1;ww<8;ww++) s4 = s4 + part2[ww][t][lane];
      int e = 16*t + l15;
      float s = si_g[e] * rsqrtf(si_v[e] + 1e-5f);
      float b1 = si_b1[e] - si_m[e];
      float bt = si_bt[e];
      float w2e = si_w2[e];
#pragma unroll
      for (int r=0;r<4;r++){
        float v = (s4[r] + b1)*s + bt;
        rowv[r] += w2e * gelu_(v);
      }
    }
    float sb2 = si_b2[0];
#pragma unroll
    for (int r=0;r<4;r++){
      float v = rowv[r];
      v += __shfl_xor(v,1); v += __shfl_xor(v,2);
      v += __shfl_xor(v,4); v += __shfl_xor(v,8);
      if (l15 == 0) smv[4*g + r] = sigmoid_(v + sb2);
    }
  }
  __syncthreads();
  const float srow = smv[l15];
  // gate + output GEMM (K chunk = w*64)
  f32x4 acc[4];
#pragma unroll
  for (int t=0;t<4;t++) acc[t] = (f32x4){0.f,0.f,0.f,0.f};
#pragma unroll
  for (int kk=0;kk<2;kk++){
    int k0 = w*64 + kk*32 + 8*g;
    bf16x8 af;
#pragma unroll
    for (int i=0;i<8;i++){
      int d = k0 + i;
      float zv = bf2f((ushort)at8[kk][i]) * srow + bf2f((ushort)cn8[kk][i]) * scm[d];
      af[i] = (short)f2bf(zv);
    }
#pragma unroll
    for (int t=0;t<4;t++){
      bf16x8 bf8 = *(const bf16x8*)(Woutb + (size_t)(16*t+l15)*512 + k0);
      acc[t] = __builtin_amdgcn_mfma_f32_16x16x32_bf16(af, bf8, acc[t], 0,0,0);
    }
  }
#pragma unroll
  for (int t=0;t<4;t++) part[w][t][lane] = acc[t];
  __syncthreads();
  if (w < 4){
    f32x4 s4 = part[0][w][lane];
#pragma unroll
    for (int ww=1;ww<8;ww++) s4 = s4 + part[ww][w][lane];
    int o = 16*w + l15;
    float bo = bout[o];
#pragma unroll
    for (int r=0;r<4;r++){
      int row = n0 + 4*g + r;
      size_t idx = (size_t)row*64 + o;
      out[idx] = s4[r] + bo + embed[idx];
    }
  }
}

extern "C" void kernel_launch(void* const* d_in, const int* in_sizes, int n_in,
                              void* d_out, int out_size, void* d_ws, size_t ws_size,
                              hipStream_t stream){
  (void)in_sizes; (void)n_in; (void)out_size;
  const float* x_in  = (const float*)d_in[0];
  const float* Wq    = (const float*)d_in[1];
  const float* Wk    = (const float*)d_in[2];
  const float* Wv    = (const float*)d_in[3];
  const float* scale = (const float*)d_in[4];
  const float* Wout  = (const float*)d_in[5];
  const float* bout  = (const float*)d_in[6];
  const float* dw_w  = (const float*)d_in[7];
  const float* dw_b  = (const float*)d_in[8];
  const float* dw_g  = (const float*)d_in[9];
  const float* dw_bt = (const float*)d_in[10];
  const float* dw_m  = (const float*)d_in[11];
  const float* dw_v  = (const float*)d_in[12];
  const float* ci_w1 = (const float*)d_in[13];
  const float* ci_b1 = (const float*)d_in[14];
  const float* ci_w2 = (const float*)d_in[15];
  const float* ci_b2 = (const float*)d_in[16];
  const float* si_w1 = (const float*)d_in[17];
  const float* si_b1 = (const float*)d_in[18];
  const float* si_g  = (const float*)d_in[19];
  const float* si_bt = (const float*)d_in[20];
  const float* si_m  = (const float*)d_in[21];
  const float* si_v  = (const float*)d_in[22];
  const float* si_w2 = (const float*)d_in[23];
  const float* si_b2 = (const float*)d_in[24];
  const float* pe_w1 = (const float*)d_in[25];
  const float* pe_w2 = (const float*)d_in[26];
  float* out = (float*)d_out;

  char* p = (char*)d_ws;
  auto alloc = [&](size_t bytes)->char*{
    char* r = p; p += (bytes + 255) & ~(size_t)255; return r;
  };
  ushort* q_bf    = (ushort*)alloc((size_t)4096*512*2);
  ushort* k_bf    = (ushort*)alloc((size_t)4096*512*2);
  ushort* vTb     = (ushort*)alloc((size_t)512*4096*2);
  ushort* att_bf  = (ushort*)alloc((size_t)4096*512*2);
  ushort* conv_x  = (ushort*)alloc((size_t)512*4096*2);
  ushort* Woutb   = (ushort*)alloc((size_t)32768*2);
  ushort* si_w1b  = (ushort*)alloc((size_t)16384*2);
  ushort* Wqb     = (ushort*)alloc((size_t)32768*2);
  ushort* Wkb     = (ushort*)alloc((size_t)32768*2);
  ushort* Wvb     = (ushort*)alloc((size_t)32768*2);
  float*  embed   = (float*) alloc((size_t)64*4096*4);
  float*  lsum_p  = (float*) alloc((size_t)8*8*4096*4);
  float*  pooled  = (float*) alloc(512*4);
  size_t used = (size_t)(p - (char*)d_ws);
  size_t segBytes = (size_t)4096*512*2 + 256;   // bf16 partials
  size_t avail = (ws_size > used) ? (ws_size - used) : 0;
  int log2S = 2;
  if (avail < 4*segBytes) log2S = 1;
  if (avail < 2*segBytes) log2S = 0;
  int S = 1 << log2S;
  ushort* O_part = (ushort*)alloc((size_t)S*segBytes);
  int NA = 128 << log2S;

  k_wcvt<<<96, 256, 0, stream>>>(Wq, Wk, Wv, Wqb, Wkb, Wvb);
  k_qkv<<<dim3(256,2), 256, 0, stream>>>(x_in, Wqb, Wkb, Wvb, scale, q_bf, k_bf, vTb,
                                         pe_w1, pe_w2, embed, Wout, si_w1,
                                         Woutb, si_w1b, pooled);
  k_attn_conv<<<NA + 512, 512, 0, stream>>>(q_bf, k_bf, vTb, O_part, lsum_p, log2S,
                                            dw_w, dw_b, dw_g, dw_bt, dw_m, dw_v,
                                            conv_x);
  if (log2S == 2)
    k_comb_t<4><<<256, 256, 0, stream>>>(O_part, lsum_p, att_bf, pooled);
  else if (log2S == 1)
    k_comb_t<2><<<256, 256, 0, stream>>>(O_part, lsum_p, att_bf, pooled);
  else
    k_comb_t<1><<<256, 256, 0, stream>>>(O_part, lsum_p, att_bf, pooled);
  k_final<<<256, 512, 0, stream>>>(att_bf, conv_x, si_w1b, si_b1, si_g, si_bt,
                                   si_m, si_v, si_w2, si_b2,
                                   pooled, ci_w1, ci_b1, ci_w2, ci_b2,
                                   Woutb, bout, embed, out);
}